// Round 5
// baseline (150.613 us; speedup 1.0000x reference)
//
#include <hip/hip_runtime.h>
#include <hip/hip_bf16.h>

// DynamicQAgent: B=4096 sessions, T=1000 steps. Sequential in T, parallel in B.
//
// Structure (R4): pack (classify to 2-bit codes, coalesced) -> ckpt (64 waves
// walk the serial scan, storing state every 32 steps; NO output traffic) ->
// emit (2048 waves, thread=(chunk,session) recomputes 32 steps from its exact
// checkpoint and stores). Checkpoints are exact f32 state -> bitwise identical.
//
// R5 change: ckpt kernel goes ALL-REGISTER (cndmask selection, no LDS LUT).
// R4 post-mortem: ckpt was 103 cy/step; ~31cy was VALU issue, ~70cy exposed
// per-step LDS LUT latency (compiler doesn't hoist indexed ds_reads; b128
// LDS throughput ~12cy/instr makes LUT no cheaper than cndmask anyway).
// At 1 wave/SIMD a serial scan is issue-bound: time = instr_count * 2cy.
// Register step1 ~20-22 instr -> predicted ckpt ~17us.

constexpr int BS = 4096;     // sessions
constexpr int TS = 1000;     // timesteps
constexpr int NW = 125;      // packed 8-step words per session
constexpr int NG4 = 32;      // uint4 groups per session (128 words, padded)
constexpr int NCH = 32;      // chunks of 32 steps (last chunk = 8 steps)
constexpr int CSTEPS = 32;

__device__ __forceinline__ float sigmoidf_(float x) {
    return 1.0f / (1.0f + expf(-x));
}

struct Params {
    float k0, k1, k2, k3;
    float a0, a1, a2, a3;
    float g0, g1;
};

__device__ __forceinline__ Params load_params(const float* __restrict__ alpha_logits,
                                              const float* __restrict__ gamma_logits,
                                              const float* __restrict__ k_vals) {
    Params P;
    P.a0 = sigmoidf_(alpha_logits[0]);
    P.a1 = sigmoidf_(alpha_logits[1]);
    P.a2 = sigmoidf_(alpha_logits[2]);
    P.a3 = sigmoidf_(alpha_logits[3]);
    P.g0 = sigmoidf_(gamma_logits[0]);
    P.g1 = sigmoidf_(gamma_logits[1]);
    P.k0 = k_vals[0];
    P.k1 = k_vals[1];
    P.k2 = k_vals[2];
    P.k3 = k_vals[3];
    return P;
}

// one scan step; math identical to R1..R4 (absmax-verified 0.0039)
__device__ __forceinline__ float2 step1(unsigned j, float& sL, float& sR, float& lam,
                                        const Params& P) {
    bool b0 = (j & 1u) != 0u;  // outcome == 0
    bool b1 = (j & 2u) != 0u;  // choice  == 0
    float k_lo = b0 ? P.k1 : P.k0;
    float k_hi = b0 ? P.k3 : P.k2;
    float a_lo = b0 ? P.a1 : P.a0;
    float a_hi = b0 ? P.a3 : P.a2;
    float gb   = b0 ? P.g1 : P.g0;
    float kj   = b1 ? k_hi : k_lo;
    float kjR  = b1 ? k_lo : k_hi;
    float aj   = b1 ? a_hi : a_lo;
    float ajR  = b1 ? a_lo : a_hi;
    float dL = kj - sL;           // old state
    float dR = kjR - sR;
    float v  = b1 ? dR : dL;      // gdiffs[j]
    sL = fmaf(dL * aj, lam, sL);
    sR = fmaf(dR * ajR, lam, sR);
    lam = fmaf(fabsf(v) - lam, gb, lam);
    return make_float2(sL, sR);
}

// --- pass 1: pack 8 steps (24 floats = 6 float4) into one u32 of 2-bit codes.
// uint4 layout: packed4[(w>>2)*BS + b] holds words 4g..4g+3 of session b.
__global__ __launch_bounds__(256) void pack_kernel(const float* __restrict__ inp,
                                                   unsigned int* __restrict__ packed) {
    int tid = blockIdx.x * blockDim.x + threadIdx.x;
    if (tid >= BS * NW) return;
    int b = tid / NW;
    int w = tid - b * NW;
    const float4* p = reinterpret_cast<const float4*>(inp + (size_t)b * (3 * TS) + (size_t)w * 24);
    float4 q0 = p[0], q1 = p[1], q2 = p[2], q3 = p[3], q4 = p[4], q5 = p[5];
    float c[8] = {q0.x, q0.w, q1.z, q2.y, q3.x, q3.w, q4.z, q5.y};
    float o[8] = {q0.z, q1.y, q2.x, q2.w, q3.z, q4.y, q5.x, q5.w};
    unsigned word = 0;
#pragma unroll
    for (int i = 0; i < 8; ++i) {
        unsigned j = ((c[i] == 0.0f) ? 2u : 0u) | ((o[i] == 0.0f) ? 1u : 0u);
        word |= j << (2 * i);
    }
    packed[(size_t)(w >> 2) * (BS * 4) + (size_t)b * 4 + (w & 3)] = word;
}

// --- pass 2: serial checkpoint walk, ALL-REGISTER. 64 blocks x 64 threads.
// Stores state BEFORE chunk c for c=0..31; walks words 0..123 (992 steps).
__global__ __launch_bounds__(64) void ckpt_kernel(const uint4* __restrict__ packed4,
                                                  const float* __restrict__ alpha_logits,
                                                  const float* __restrict__ gamma_logits,
                                                  const float* __restrict__ k_vals,
                                                  float4* __restrict__ ckpt) {
    const int l = threadIdx.x;
    const int b = blockIdx.x * 64 + l;
    const Params P = load_params(alpha_logits, gamma_logits, k_vals);

    float sL = 0.0f, sR = 0.0f, lam = 0.5f;
    const uint4* pp = packed4 + b;
    uint4 cur = pp[0];

    for (int c = 0; c < NCH - 1; ++c) {
        ckpt[(size_t)c * BS + b] = make_float4(sL, sR, lam, 0.0f);
        uint4 nxt = pp[(size_t)(c + 1) * BS];    // prefetch next group
        const unsigned words[4] = {cur.x, cur.y, cur.z, cur.w};
#pragma unroll
        for (int q = 0; q < 4; ++q) {
            unsigned w = words[q];
#pragma unroll
            for (int i = 0; i < 8; ++i) {
                step1((w >> (2 * i)) & 3u, sL, sR, lam, P);
            }
        }
        cur = nxt;
    }
    ckpt[(size_t)(NCH - 1) * BS + b] = make_float4(sL, sR, lam, 0.0f);
}

// --- pass 3: parallel emit. thread = (chunk c, session b); 512 blocks x 256.
__global__ __launch_bounds__(256) void emit_kernel(const uint4* __restrict__ packed4,
                                                   const float4* __restrict__ ckpt,
                                                   const float* __restrict__ alpha_logits,
                                                   const float* __restrict__ gamma_logits,
                                                   const float* __restrict__ k_vals,
                                                   float* __restrict__ out) {
    int tid = blockIdx.x * 256 + threadIdx.x;
    int c = tid >> 12;        // /4096  (block-uniform)
    int b = tid & 4095;
    const Params P = load_params(alpha_logits, gamma_logits, k_vals);

    float4 st = ckpt[(size_t)c * BS + b];        // coalesced
    float sL = st.x, sR = st.y, lam = st.z;
    uint4 cw = packed4[(size_t)c * BS + b];      // coalesced
    const unsigned words[4] = {cw.x, cw.y, cw.z, cw.w};

    float* ob = out + (size_t)b * (2 * TS) + (size_t)c * (2 * CSTEPS);
    const int nq = (c == NCH - 1) ? 1 : 4;       // last chunk = 8 steps

    for (int q = 0; q < nq; ++q) {
        unsigned w = words[q];
#pragma unroll
        for (int i = 0; i < 8; i += 2) {
            float2 r0 = step1((w >> (2 * i)) & 3u, sL, sR, lam, P);
            float2 r1 = step1((w >> (2 * i + 2)) & 3u, sL, sR, lam, P);
            *reinterpret_cast<float4*>(ob + q * 16 + i * 2) =
                make_float4(r0.x, r0.y, r1.x, r1.y);
        }
    }
}

// --- fallback if ws too small: read inp directly (uncoalesced but correct)
__global__ __launch_bounds__(64) void scan_fused(const float* __restrict__ inp,
                                                 const float* __restrict__ alpha_logits,
                                                 const float* __restrict__ gamma_logits,
                                                 const float* __restrict__ k_vals,
                                                 float* __restrict__ out) {
    int b = blockIdx.x * 64 + threadIdx.x;
    const Params P = load_params(alpha_logits, gamma_logits, k_vals);
    float sL = 0.0f, sR = 0.0f, lam = 0.5f;
    float* op = out + (size_t)b * (2 * TS);
    for (int w = 0; w < NW; ++w) {
        const float4* p = reinterpret_cast<const float4*>(inp + (size_t)b * (3 * TS) + (size_t)w * 24);
        float4 q0 = p[0], q1 = p[1], q2 = p[2], q3 = p[3], q4 = p[4], q5 = p[5];
        float c[8] = {q0.x, q0.w, q1.z, q2.y, q3.x, q3.w, q4.z, q5.y};
        float o[8] = {q0.z, q1.y, q2.x, q2.w, q3.z, q4.y, q5.x, q5.w};
#pragma unroll
        for (int i = 0; i < 8; ++i) {
            unsigned j = ((c[i] == 0.0f) ? 2u : 0u) | ((o[i] == 0.0f) ? 1u : 0u);
            reinterpret_cast<float2*>(op)[w * 8 + i] = step1(j, sL, sR, lam, P);
        }
    }
}

extern "C" void kernel_launch(void* const* d_in, const int* in_sizes, int n_in,
                              void* d_out, int out_size, void* d_ws, size_t ws_size,
                              hipStream_t stream) {
    const float* inp          = (const float*)d_in[0];
    const float* alpha_logits = (const float*)d_in[1];
    const float* gamma_logits = (const float*)d_in[2];
    const float* k_vals       = (const float*)d_in[3];
    float* out = (float*)d_out;

    const size_t packedB = (size_t)NG4 * BS * 4 * sizeof(unsigned int);  // 2 MiB
    const size_t ckptB   = (size_t)NCH * BS * sizeof(float4);            // 2 MiB

    if (ws_size >= packedB + ckptB) {
        unsigned int* packed = (unsigned int*)d_ws;
        float4* ckpt = (float4*)((char*)d_ws + packedB);
        int total = BS * NW;
        pack_kernel<<<(total + 255) / 256, 256, 0, stream>>>(inp, packed);
        ckpt_kernel<<<BS / 64, 64, 0, stream>>>((const uint4*)packed, alpha_logits,
                                                gamma_logits, k_vals, ckpt);
        emit_kernel<<<(NCH * BS) / 256, 256, 0, stream>>>((const uint4*)packed, ckpt,
                                                          alpha_logits, gamma_logits,
                                                          k_vals, out);
    } else {
        scan_fused<<<BS / 64, 64, 0, stream>>>(inp, alpha_logits, gamma_logits, k_vals, out);
    }
}

// Round 6
// 77.553 us; speedup vs baseline: 1.9421x; 1.9421x over previous
//
#include <hip/hip_runtime.h>
#include <hip/hip_bf16.h>

// DynamicQAgent: B=4096 sessions, T=1000 steps. Sequential in T, parallel in B.
//
// Structure (since R4): pack (classify steps to 2-bit codes, coalesced) ->
// ckpt (64 waves walk the serial scan storing exact f32 state every 32 steps)
// -> emit (2048 waves, thread=(chunk,session) recomputes 32 steps from its
// checkpoint and stores output). Checkpoints exact -> bitwise identical.
//
// R6 change: ALL selection via integer bitwise-select (v_bfi), no float
// ternaries. R5 post-mortem: hipcc turned the 10 data-dependent ternaries
// into ~115 VALU-issues/step (divergent branch tree or vcc serialization),
// 3.4x slower than the R4 LDS LUT. bfi select: mask = -(bit), one VALU op
// per select, no vcc, no branches, moves exact bit patterns (bit-identical).

constexpr int BS = 4096;     // sessions
constexpr int TS = 1000;     // timesteps
constexpr int NW = 125;      // packed 8-step words per session
constexpr int NG4 = 32;      // uint4 groups per session (128 words, padded)
constexpr int NCH = 32;      // chunks of 32 steps (last chunk = 8 steps)
constexpr int CSTEPS = 32;

__device__ __forceinline__ float sigmoidf_(float x) {
    return 1.0f / (1.0f + expf(-x));
}

struct Params {
    float k0, k1, k2, k3;
    float a0, a1, a2, a3;
    float g0, g1;
};

__device__ __forceinline__ Params load_params(const float* __restrict__ alpha_logits,
                                              const float* __restrict__ gamma_logits,
                                              const float* __restrict__ k_vals) {
    Params P;
    P.a0 = sigmoidf_(alpha_logits[0]);
    P.a1 = sigmoidf_(alpha_logits[1]);
    P.a2 = sigmoidf_(alpha_logits[2]);
    P.a3 = sigmoidf_(alpha_logits[3]);
    P.g0 = sigmoidf_(gamma_logits[0]);
    P.g1 = sigmoidf_(gamma_logits[1]);
    P.k0 = k_vals[0];
    P.k1 = k_vals[1];
    P.k2 = k_vals[2];
    P.k3 = k_vals[3];
    return P;
}

// bitwise select: m == -1 -> a, m == 0 -> b. Exact bit move; maps to v_bfi_b32.
__device__ __forceinline__ float fsel(int m, float a, float b) {
    int ia = __float_as_int(a);
    int ib = __float_as_int(b);
    return __int_as_float(ib ^ ((ia ^ ib) & m));
}

// one scan step, bfi-select version; math bit-identical to R1..R5 step
// (selection moves exact bit patterns; arithmetic ops unchanged).
__device__ __forceinline__ float2 step_b(unsigned w, int i, float& sL, float& sR,
                                         float& lam, const Params& P) {
    int m0 = -(int)((w >> (2 * i)) & 1u);       // outcome == 0 mask
    int m1 = -(int)((w >> (2 * i + 1)) & 1u);   // choice  == 0 mask
    float k_lo = fsel(m0, P.k1, P.k0);
    float k_hi = fsel(m0, P.k3, P.k2);
    float a_lo = fsel(m0, P.a1, P.a0);
    float a_hi = fsel(m0, P.a3, P.a2);
    float gb   = fsel(m0, P.g1, P.g0);
    float kj   = fsel(m1, k_hi, k_lo);
    float kjR  = fsel(m1, k_lo, k_hi);
    float aj   = fsel(m1, a_hi, a_lo);
    float ajR  = fsel(m1, a_lo, a_hi);
    float dL = kj - sL;           // old state
    float dR = kjR - sR;
    float v  = fsel(m1, dR, dL);  // gdiffs[j]
    sL = fmaf(dL * aj, lam, sL);
    sR = fmaf(dR * ajR, lam, sR);
    lam = fmaf(fabsf(v) - lam, gb, lam);
    return make_float2(sL, sR);
}

// --- pass 1: pack 8 steps (24 floats = 6 float4) into one u32 of 2-bit codes.
// uint4 layout: packed4[(w>>2)*BS + b] holds words 4g..4g+3 of session b.
__global__ __launch_bounds__(256) void pack_kernel(const float* __restrict__ inp,
                                                   unsigned int* __restrict__ packed) {
    int tid = blockIdx.x * blockDim.x + threadIdx.x;
    if (tid >= BS * NW) return;
    int b = tid / NW;
    int w = tid - b * NW;
    const float4* p = reinterpret_cast<const float4*>(inp + (size_t)b * (3 * TS) + (size_t)w * 24);
    float4 q0 = p[0], q1 = p[1], q2 = p[2], q3 = p[3], q4 = p[4], q5 = p[5];
    float c[8] = {q0.x, q0.w, q1.z, q2.y, q3.x, q3.w, q4.z, q5.y};
    float o[8] = {q0.z, q1.y, q2.x, q2.w, q3.z, q4.y, q5.x, q5.w};
    unsigned word = 0;
#pragma unroll
    for (int i = 0; i < 8; ++i) {
        unsigned j = ((c[i] == 0.0f) ? 2u : 0u) | ((o[i] == 0.0f) ? 1u : 0u);
        word |= j << (2 * i);
    }
    packed[(size_t)(w >> 2) * (BS * 4) + (size_t)b * 4 + (w & 3)] = word;
}

// --- pass 2: serial checkpoint walk, bfi-select, all-register.
// 64 blocks x 64 threads, thread = session. Stores state BEFORE chunk c,
// c = 0..31; walks words 0..123 (992 steps). Group 31's words 125..127 are
// never used in math.
__global__ __launch_bounds__(64) void ckpt_kernel(const uint4* __restrict__ packed4,
                                                  const float* __restrict__ alpha_logits,
                                                  const float* __restrict__ gamma_logits,
                                                  const float* __restrict__ k_vals,
                                                  float4* __restrict__ ckpt) {
    const int l = threadIdx.x;
    const int b = blockIdx.x * 64 + l;
    const Params P = load_params(alpha_logits, gamma_logits, k_vals);

    float sL = 0.0f, sR = 0.0f, lam = 0.5f;
    const uint4* pp = packed4 + b;
    uint4 cur = pp[0];

    for (int c = 0; c < NCH - 1; ++c) {
        ckpt[(size_t)c * BS + b] = make_float4(sL, sR, lam, 0.0f);
        uint4 nxt = pp[(size_t)(c + 1) * BS];    // prefetch next group
        const unsigned words[4] = {cur.x, cur.y, cur.z, cur.w};
#pragma unroll
        for (int q = 0; q < 4; ++q) {
            unsigned w = words[q];
#pragma unroll
            for (int i = 0; i < 8; ++i) {
                step_b(w, i, sL, sR, lam, P);
            }
        }
        cur = nxt;
    }
    ckpt[(size_t)(NCH - 1) * BS + b] = make_float4(sL, sR, lam, 0.0f);
}

// --- pass 3: parallel emit. thread = (chunk c, session b); 512 blocks x 256.
__global__ __launch_bounds__(256) void emit_kernel(const uint4* __restrict__ packed4,
                                                   const float4* __restrict__ ckpt,
                                                   const float* __restrict__ alpha_logits,
                                                   const float* __restrict__ gamma_logits,
                                                   const float* __restrict__ k_vals,
                                                   float* __restrict__ out) {
    int tid = blockIdx.x * 256 + threadIdx.x;
    int c = tid >> 12;        // /4096  (block-uniform)
    int b = tid & 4095;
    const Params P = load_params(alpha_logits, gamma_logits, k_vals);

    float4 st = ckpt[(size_t)c * BS + b];        // coalesced
    float sL = st.x, sR = st.y, lam = st.z;
    uint4 cw = packed4[(size_t)c * BS + b];      // coalesced
    const unsigned words[4] = {cw.x, cw.y, cw.z, cw.w};

    float* ob = out + (size_t)b * (2 * TS) + (size_t)c * (2 * CSTEPS);
    const int nq = (c == NCH - 1) ? 1 : 4;       // last chunk = 8 steps

    for (int q = 0; q < nq; ++q) {
        unsigned w = words[q];
#pragma unroll
        for (int i = 0; i < 8; i += 2) {
            float2 r0 = step_b(w, i, sL, sR, lam, P);
            float2 r1 = step_b(w, i + 1, sL, sR, lam, P);
            *reinterpret_cast<float4*>(ob + q * 16 + i * 2) =
                make_float4(r0.x, r0.y, r1.x, r1.y);
        }
    }
}

// --- fallback if ws too small: read inp directly (uncoalesced but correct)
__global__ __launch_bounds__(64) void scan_fused(const float* __restrict__ inp,
                                                 const float* __restrict__ alpha_logits,
                                                 const float* __restrict__ gamma_logits,
                                                 const float* __restrict__ k_vals,
                                                 float* __restrict__ out) {
    int b = blockIdx.x * 64 + threadIdx.x;
    const Params P = load_params(alpha_logits, gamma_logits, k_vals);
    float sL = 0.0f, sR = 0.0f, lam = 0.5f;
    float* op = out + (size_t)b * (2 * TS);
    for (int w = 0; w < NW; ++w) {
        const float4* p = reinterpret_cast<const float4*>(inp + (size_t)b * (3 * TS) + (size_t)w * 24);
        float4 q0 = p[0], q1 = p[1], q2 = p[2], q3 = p[3], q4 = p[4], q5 = p[5];
        float c[8] = {q0.x, q0.w, q1.z, q2.y, q3.x, q3.w, q4.z, q5.y};
        float o[8] = {q0.z, q1.y, q2.x, q2.w, q3.z, q4.y, q5.x, q5.w};
        unsigned word = 0;
#pragma unroll
        for (int i = 0; i < 8; ++i) {
            unsigned j = ((c[i] == 0.0f) ? 2u : 0u) | ((o[i] == 0.0f) ? 1u : 0u);
            word |= j << (2 * i);
        }
#pragma unroll
        for (int i = 0; i < 8; ++i) {
            float2 r = step_b(word, i, sL, sR, lam, P);
            reinterpret_cast<float2*>(op)[w * 8 + i] = r;
        }
    }
}

extern "C" void kernel_launch(void* const* d_in, const int* in_sizes, int n_in,
                              void* d_out, int out_size, void* d_ws, size_t ws_size,
                              hipStream_t stream) {
    const float* inp          = (const float*)d_in[0];
    const float* alpha_logits = (const float*)d_in[1];
    const float* gamma_logits = (const float*)d_in[2];
    const float* k_vals       = (const float*)d_in[3];
    float* out = (float*)d_out;

    const size_t packedB = (size_t)NG4 * BS * 4 * sizeof(unsigned int);  // 2 MiB
    const size_t ckptB   = (size_t)NCH * BS * sizeof(float4);            // 2 MiB

    if (ws_size >= packedB + ckptB) {
        unsigned int* packed = (unsigned int*)d_ws;
        float4* ckpt = (float4*)((char*)d_ws + packedB);
        int total = BS * NW;
        pack_kernel<<<(total + 255) / 256, 256, 0, stream>>>(inp, packed);
        ckpt_kernel<<<BS / 64, 64, 0, stream>>>((const uint4*)packed, alpha_logits,
                                                gamma_logits, k_vals, ckpt);
        emit_kernel<<<(NCH * BS) / 256, 256, 0, stream>>>((const uint4*)packed, ckpt,
                                                          alpha_logits, gamma_logits,
                                                          k_vals, out);
    } else {
        scan_fused<<<BS / 64, 64, 0, stream>>>(inp, alpha_logits, gamma_logits, k_vals, out);
    }
}

// Round 7
// 73.064 us; speedup vs baseline: 2.0614x; 1.0614x over previous
//
#include <hip/hip_runtime.h>
#include <hip/hip_bf16.h>

// DynamicQAgent: B=4096 sessions, T=1000 steps. Sequential in T, parallel in B.
//
// Structure (since R4): pack (classify steps to 2-bit codes, coalesced) ->
// ckpt (64 waves walk the serial scan storing exact f32 state every 32 steps)
// -> emit (2048 waves, thread=(chunk,session) recomputes 32 steps from its
// checkpoint and stores output). Checkpoints exact -> bitwise identical.
//
// R7 change: selects via inline-asm v_bfi_b32 (1 instr each). R6 post-mortem:
// hipcc does NOT pattern-match b^((a^b)&m) to bfi; each fsel was a serial
// 3-op chain (xor-and-xor) and the nested select tree became a ~6-deep
// dependent chain -> 39 instr/step + 70cy/step exposed latency. bfi selects
// depend only on the code word, so the scheduler can hoist them off the
// state-recurrence chain entirely. Bit-identical (selects move exact bits).

constexpr int BS = 4096;     // sessions
constexpr int TS = 1000;     // timesteps
constexpr int NW = 125;      // packed 8-step words per session
constexpr int NG4 = 32;      // uint4 groups per session (128 words, padded)
constexpr int NCH = 32;      // chunks of 32 steps (last chunk = 8 steps)
constexpr int CSTEPS = 32;

__device__ __forceinline__ float sigmoidf_(float x) {
    return 1.0f / (1.0f + expf(-x));
}

struct Params {
    float k0, k1, k2, k3;
    float a0, a1, a2, a3;
    float g0, g1;
};

__device__ __forceinline__ Params load_params(const float* __restrict__ alpha_logits,
                                              const float* __restrict__ gamma_logits,
                                              const float* __restrict__ k_vals) {
    Params P;
    P.a0 = sigmoidf_(alpha_logits[0]);
    P.a1 = sigmoidf_(alpha_logits[1]);
    P.a2 = sigmoidf_(alpha_logits[2]);
    P.a3 = sigmoidf_(alpha_logits[3]);
    P.g0 = sigmoidf_(gamma_logits[0]);
    P.g1 = sigmoidf_(gamma_logits[1]);
    P.k0 = k_vals[0];
    P.k1 = k_vals[1];
    P.k2 = k_vals[2];
    P.k3 = k_vals[3];
    return P;
}

// single-instruction bitfield-select: D = (m & a) | (~m & b).
// m == -1 -> a, m == 0 -> b. Exact bit move -> float-value preserving.
__device__ __forceinline__ float bfi_sel(int m, float a, float b) {
    float r;
    asm("v_bfi_b32 %0, %1, %2, %3" : "=v"(r) : "v"(m), "v"(a), "v"(b));
    return r;
}

// mask = -(bit at position p of w); shl/ashr idiom folds to v_bfe_i32.
__device__ __forceinline__ int bitmask_(unsigned w, int p) {
    return ((int)(w << (31 - p))) >> 31;
}

// one scan step; math bit-identical to R1..R6 (selection moves exact bit
// patterns; arithmetic ops unchanged). absmax-verified 0.0039.
__device__ __forceinline__ float2 step_b(unsigned w, int i, float& sL, float& sR,
                                         float& lam, const Params& P) {
    int m0 = bitmask_(w, 2 * i);         // outcome == 0 mask
    int m1 = bitmask_(w, 2 * i + 1);     // choice  == 0 mask
    float k_lo = bfi_sel(m0, P.k1, P.k0);
    float k_hi = bfi_sel(m0, P.k3, P.k2);
    float a_lo = bfi_sel(m0, P.a1, P.a0);
    float a_hi = bfi_sel(m0, P.a3, P.a2);
    float gb   = bfi_sel(m0, P.g1, P.g0);
    float kj   = bfi_sel(m1, k_hi, k_lo);
    float kjR  = bfi_sel(m1, k_lo, k_hi);
    float aj   = bfi_sel(m1, a_hi, a_lo);
    float ajR  = bfi_sel(m1, a_lo, a_hi);
    float dL = kj - sL;                  // old state
    float dR = kjR - sR;
    float v  = bfi_sel(m1, dR, dL);      // gdiffs[j]
    sL = fmaf(dL * aj, lam, sL);
    sR = fmaf(dR * ajR, lam, sR);
    lam = fmaf(fabsf(v) - lam, gb, lam);
    return make_float2(sL, sR);
}

// --- pass 1: pack 8 steps (24 floats = 6 float4) into one u32 of 2-bit codes.
// uint4 layout: packed4[(w>>2)*BS + b] holds words 4g..4g+3 of session b.
__global__ __launch_bounds__(256) void pack_kernel(const float* __restrict__ inp,
                                                   unsigned int* __restrict__ packed) {
    int tid = blockIdx.x * blockDim.x + threadIdx.x;
    if (tid >= BS * NW) return;
    int b = tid / NW;
    int w = tid - b * NW;
    const float4* p = reinterpret_cast<const float4*>(inp + (size_t)b * (3 * TS) + (size_t)w * 24);
    float4 q0 = p[0], q1 = p[1], q2 = p[2], q3 = p[3], q4 = p[4], q5 = p[5];
    float c[8] = {q0.x, q0.w, q1.z, q2.y, q3.x, q3.w, q4.z, q5.y};
    float o[8] = {q0.z, q1.y, q2.x, q2.w, q3.z, q4.y, q5.x, q5.w};
    unsigned word = 0;
#pragma unroll
    for (int i = 0; i < 8; ++i) {
        unsigned j = ((c[i] == 0.0f) ? 2u : 0u) | ((o[i] == 0.0f) ? 1u : 0u);
        word |= j << (2 * i);
    }
    packed[(size_t)(w >> 2) * (BS * 4) + (size_t)b * 4 + (w & 3)] = word;
}

// --- pass 2: serial checkpoint walk, bfi-asm selects, all-register.
// 64 blocks x 64 threads, thread = session. Stores state BEFORE chunk c,
// c = 0..31; walks words 0..123 (992 steps).
__global__ __launch_bounds__(64) void ckpt_kernel(const uint4* __restrict__ packed4,
                                                  const float* __restrict__ alpha_logits,
                                                  const float* __restrict__ gamma_logits,
                                                  const float* __restrict__ k_vals,
                                                  float4* __restrict__ ckpt) {
    const int l = threadIdx.x;
    const int b = blockIdx.x * 64 + l;
    const Params P = load_params(alpha_logits, gamma_logits, k_vals);

    float sL = 0.0f, sR = 0.0f, lam = 0.5f;
    const uint4* pp = packed4 + b;
    uint4 cur = pp[0];

    for (int c = 0; c < NCH - 1; ++c) {
        ckpt[(size_t)c * BS + b] = make_float4(sL, sR, lam, 0.0f);
        uint4 nxt = pp[(size_t)(c + 1) * BS];    // prefetch next group
        const unsigned words[4] = {cur.x, cur.y, cur.z, cur.w};
#pragma unroll
        for (int q = 0; q < 4; ++q) {
            unsigned w = words[q];
#pragma unroll
            for (int i = 0; i < 8; ++i) {
                step_b(w, i, sL, sR, lam, P);
            }
        }
        cur = nxt;
    }
    ckpt[(size_t)(NCH - 1) * BS + b] = make_float4(sL, sR, lam, 0.0f);
}

// --- pass 3: parallel emit. thread = (chunk c, session b); 512 blocks x 256.
__global__ __launch_bounds__(256) void emit_kernel(const uint4* __restrict__ packed4,
                                                   const float4* __restrict__ ckpt,
                                                   const float* __restrict__ alpha_logits,
                                                   const float* __restrict__ gamma_logits,
                                                   const float* __restrict__ k_vals,
                                                   float* __restrict__ out) {
    int tid = blockIdx.x * 256 + threadIdx.x;
    int c = tid >> 12;        // /4096  (block-uniform)
    int b = tid & 4095;
    const Params P = load_params(alpha_logits, gamma_logits, k_vals);

    float4 st = ckpt[(size_t)c * BS + b];        // coalesced
    float sL = st.x, sR = st.y, lam = st.z;
    uint4 cw = packed4[(size_t)c * BS + b];      // coalesced
    const unsigned words[4] = {cw.x, cw.y, cw.z, cw.w};

    float* ob = out + (size_t)b * (2 * TS) + (size_t)c * (2 * CSTEPS);
    const int nq = (c == NCH - 1) ? 1 : 4;       // last chunk = 8 steps

    for (int q = 0; q < nq; ++q) {
        unsigned w = words[q];
#pragma unroll
        for (int i = 0; i < 8; i += 2) {
            float2 r0 = step_b(w, i, sL, sR, lam, P);
            float2 r1 = step_b(w, i + 1, sL, sR, lam, P);
            *reinterpret_cast<float4*>(ob + q * 16 + i * 2) =
                make_float4(r0.x, r0.y, r1.x, r1.y);
        }
    }
}

// --- fallback if ws too small: read inp directly (uncoalesced but correct)
__global__ __launch_bounds__(64) void scan_fused(const float* __restrict__ inp,
                                                 const float* __restrict__ alpha_logits,
                                                 const float* __restrict__ gamma_logits,
                                                 const float* __restrict__ k_vals,
                                                 float* __restrict__ out) {
    int b = blockIdx.x * 64 + threadIdx.x;
    const Params P = load_params(alpha_logits, gamma_logits, k_vals);
    float sL = 0.0f, sR = 0.0f, lam = 0.5f;
    float* op = out + (size_t)b * (2 * TS);
    for (int w = 0; w < NW; ++w) {
        const float4* p = reinterpret_cast<const float4*>(inp + (size_t)b * (3 * TS) + (size_t)w * 24);
        float4 q0 = p[0], q1 = p[1], q2 = p[2], q3 = p[3], q4 = p[4], q5 = p[5];
        float c[8] = {q0.x, q0.w, q1.z, q2.y, q3.x, q3.w, q4.z, q5.y};
        float o[8] = {q0.z, q1.y, q2.x, q2.w, q3.z, q4.y, q5.x, q5.w};
        unsigned word = 0;
#pragma unroll
        for (int i = 0; i < 8; ++i) {
            unsigned j = ((c[i] == 0.0f) ? 2u : 0u) | ((o[i] == 0.0f) ? 1u : 0u);
            word |= j << (2 * i);
        }
#pragma unroll
        for (int i = 0; i < 8; ++i) {
            float2 r = step_b(word, i, sL, sR, lam, P);
            reinterpret_cast<float2*>(op)[w * 8 + i] = r;
        }
    }
}

extern "C" void kernel_launch(void* const* d_in, const int* in_sizes, int n_in,
                              void* d_out, int out_size, void* d_ws, size_t ws_size,
                              hipStream_t stream) {
    const float* inp          = (const float*)d_in[0];
    const float* alpha_logits = (const float*)d_in[1];
    const float* gamma_logits = (const float*)d_in[2];
    const float* k_vals       = (const float*)d_in[3];
    float* out = (float*)d_out;

    const size_t packedB = (size_t)NG4 * BS * 4 * sizeof(unsigned int);  // 2 MiB
    const size_t ckptB   = (size_t)NCH * BS * sizeof(float4);            // 2 MiB

    if (ws_size >= packedB + ckptB) {
        unsigned int* packed = (unsigned int*)d_ws;
        float4* ckpt = (float4*)((char*)d_ws + packedB);
        int total = BS * NW;
        pack_kernel<<<(total + 255) / 256, 256, 0, stream>>>(inp, packed);
        ckpt_kernel<<<BS / 64, 64, 0, stream>>>((const uint4*)packed, alpha_logits,
                                                gamma_logits, k_vals, ckpt);
        emit_kernel<<<(NCH * BS) / 256, 256, 0, stream>>>((const uint4*)packed, ckpt,
                                                          alpha_logits, gamma_logits,
                                                          k_vals, out);
    } else {
        scan_fused<<<BS / 64, 64, 0, stream>>>(inp, alpha_logits, gamma_logits, k_vals, out);
    }
}

// Round 8
// 34.318 us; speedup vs baseline: 4.3887x; 2.1290x over previous
//
#include <hip/hip_runtime.h>
#include <hip/hip_bf16.h>

// DynamicQAgent: B=4096 sessions, T=1000 steps. Sequential in T, parallel in B.
//
// R8 structure: pack -> scan_spec (speculative chunked scan, NO serial pass).
// R4-R7 lesson: a 1-wave/SIMD serial chain runs at ~7-12cy per dependent VALU
// instr regardless of instruction mix (LUT 103cy/step, ternaries 294,
// xor-select 148, bfi 138) -- latency can only be COVERED by other waves,
// never removed. So: 16 chunks/session, each chunk-thread starts <=192 steps
// early from the guess (0,0,0.5) and relies on the recurrence's contraction
// (lam' = (1-g)lam + g|v| contracts (1-g)/step; sL' likewise (1-a*lam)/step;
// 0.9^192 ~ 2e-9) to converge to the exact state before its store region.
// Chunks 0..3 start at t=0 and are exact. 65536 threads = 4 waves/SIMD.

constexpr int BS = 4096;     // sessions
constexpr int TS = 1000;     // timesteps
constexpr int NW = 125;      // packed 8-step words per session
constexpr int NG4 = 32;      // uint4 groups per session (128 words, padded)
constexpr int NSPC = 16;     // speculative chunks per session (8 words each)
constexpr int WWARM = 24;    // warmup words (192 steps) before store region

__device__ __forceinline__ float sigmoidf_(float x) {
    return 1.0f / (1.0f + expf(-x));
}

struct Params {
    float k0, k1, k2, k3;
    float a0, a1, a2, a3;
    float g0, g1;
};

__device__ __forceinline__ Params load_params(const float* __restrict__ alpha_logits,
                                              const float* __restrict__ gamma_logits,
                                              const float* __restrict__ k_vals) {
    Params P;
    P.a0 = sigmoidf_(alpha_logits[0]);
    P.a1 = sigmoidf_(alpha_logits[1]);
    P.a2 = sigmoidf_(alpha_logits[2]);
    P.a3 = sigmoidf_(alpha_logits[3]);
    P.g0 = sigmoidf_(gamma_logits[0]);
    P.g1 = sigmoidf_(gamma_logits[1]);
    P.k0 = k_vals[0];
    P.k1 = k_vals[1];
    P.k2 = k_vals[2];
    P.k3 = k_vals[3];
    return P;
}

// single-instruction bitfield-select: D = (m & a) | (~m & b). Exact bit move.
__device__ __forceinline__ float bfi_sel(int m, float a, float b) {
    float r;
    asm("v_bfi_b32 %0, %1, %2, %3" : "=v"(r) : "v"(m), "v"(a), "v"(b));
    return r;
}

// mask = -(bit at position p of w)
__device__ __forceinline__ int bitmask_(unsigned w, int p) {
    return ((int)(w << (31 - p))) >> 31;
}

// one scan step; math bit-identical to R1..R7 (absmax-verified 0.0039)
__device__ __forceinline__ float2 step_b(unsigned w, int i, float& sL, float& sR,
                                         float& lam, const Params& P) {
    int m0 = bitmask_(w, 2 * i);         // outcome == 0 mask
    int m1 = bitmask_(w, 2 * i + 1);     // choice  == 0 mask
    float k_lo = bfi_sel(m0, P.k1, P.k0);
    float k_hi = bfi_sel(m0, P.k3, P.k2);
    float a_lo = bfi_sel(m0, P.a1, P.a0);
    float a_hi = bfi_sel(m0, P.a3, P.a2);
    float gb   = bfi_sel(m0, P.g1, P.g0);
    float kj   = bfi_sel(m1, k_hi, k_lo);
    float kjR  = bfi_sel(m1, k_lo, k_hi);
    float aj   = bfi_sel(m1, a_hi, a_lo);
    float ajR  = bfi_sel(m1, a_lo, a_hi);
    float dL = kj - sL;                  // old state
    float dR = kjR - sR;
    float v  = bfi_sel(m1, dR, dL);      // gdiffs[j]
    sL = fmaf(dL * aj, lam, sL);
    sR = fmaf(dR * ajR, lam, sR);
    lam = fmaf(fabsf(v) - lam, gb, lam);
    return make_float2(sL, sR);
}

// --- pass 1: pack 8 steps (24 floats = 6 float4) into one u32 of 2-bit codes.
// uint4 layout: packed4[(w>>2)*BS + b] holds words 4g..4g+3 of session b.
__global__ __launch_bounds__(256) void pack_kernel(const float* __restrict__ inp,
                                                   unsigned int* __restrict__ packed) {
    int tid = blockIdx.x * blockDim.x + threadIdx.x;
    if (tid >= BS * NW) return;
    int b = tid / NW;
    int w = tid - b * NW;
    const float4* p = reinterpret_cast<const float4*>(inp + (size_t)b * (3 * TS) + (size_t)w * 24);
    float4 q0 = p[0], q1 = p[1], q2 = p[2], q3 = p[3], q4 = p[4], q5 = p[5];
    float c[8] = {q0.x, q0.w, q1.z, q2.y, q3.x, q3.w, q4.z, q5.y};
    float o[8] = {q0.z, q1.y, q2.x, q2.w, q3.z, q4.y, q5.x, q5.w};
    unsigned word = 0;
#pragma unroll
    for (int i = 0; i < 8; ++i) {
        unsigned j = ((c[i] == 0.0f) ? 2u : 0u) | ((o[i] == 0.0f) ? 1u : 0u);
        word |= j << (2 * i);
    }
    packed[(size_t)(w >> 2) * (BS * 4) + (size_t)b * 4 + (w & 3)] = word;
}

// --- pass 2: speculative chunked scan. thread = (chunk c, session b).
// 65536 threads = 1024 waves = 4 waves/SIMD. c is wave-uniform.
// Chunk c stores words [8c, min(8c+8,125)), warming up from word
// max(0, 8c-24) starting at the exact-init guess (0, 0, 0.5).
__global__ __launch_bounds__(256, 4) void scan_spec(const uint4* __restrict__ packed4,
                                                    const float* __restrict__ alpha_logits,
                                                    const float* __restrict__ gamma_logits,
                                                    const float* __restrict__ k_vals,
                                                    float* __restrict__ out) {
    const int tid = blockIdx.x * 256 + threadIdx.x;
    const int b = tid & (BS - 1);
    const int c = tid >> 12;              // 0..15, wave-uniform
    const Params P = load_params(alpha_logits, gamma_logits, k_vals);

    float sL = 0.0f, sR = 0.0f, lam = 0.5f;

    const int cw0 = c * 8;                          // first stored word
    const int sw = (cw0 - WWARM > 0) ? (cw0 - WWARM) : 0;  // start word (mult of 8)
    const int gc = cw0 >> 2;                        // first store group
    const uint4* pp = packed4 + b;

    // warmup: groups sw/4 .. gc-1 (wave-uniform trip count), prefetched
    uint4 cur = pp[(size_t)(sw >> 2) * BS];
    for (int g = sw >> 2; g < gc; ++g) {
        uint4 nxt = pp[(size_t)(g + 1) * BS];
        const unsigned words[4] = {cur.x, cur.y, cur.z, cur.w};
#pragma unroll
        for (int q = 0; q < 4; ++q) {
#pragma unroll
            for (int i = 0; i < 8; ++i) {
                step_b(words[q], i, sL, sR, lam, P);
            }
        }
        cur = nxt;
    }

    // store region: group gc (= cur after loop) and gc+1
    uint4 nxt2 = pp[(size_t)(gc + 1) * BS];         // gc+1 <= 31, padded region ok
    float* ob = out + (size_t)b * (2 * TS) + (size_t)cw0 * 16;

    {
        const unsigned words[4] = {cur.x, cur.y, cur.z, cur.w};
#pragma unroll
        for (int q = 0; q < 4; ++q) {
#pragma unroll
            for (int i = 0; i < 8; i += 2) {
                float2 r0 = step_b(words[q], i, sL, sR, lam, P);
                float2 r1 = step_b(words[q], i + 1, sL, sR, lam, P);
                *reinterpret_cast<float4*>(ob + q * 16 + i * 2) =
                    make_float4(r0.x, r0.y, r1.x, r1.y);
            }
        }
    }
    ob += 64;
    {
        const int nw2 = (c == NSPC - 1) ? 1 : 4;    // c=15: only word 124 remains
        const unsigned words[4] = {nxt2.x, nxt2.y, nxt2.z, nxt2.w};
#pragma unroll
        for (int q = 0; q < 4; ++q) {
            if (q < nw2) {                           // wave-uniform branch
#pragma unroll
                for (int i = 0; i < 8; i += 2) {
                    float2 r0 = step_b(words[q], i, sL, sR, lam, P);
                    float2 r1 = step_b(words[q], i + 1, sL, sR, lam, P);
                    *reinterpret_cast<float4*>(ob + q * 16 + i * 2) =
                        make_float4(r0.x, r0.y, r1.x, r1.y);
                }
            }
        }
    }
}

// --- fallback if ws too small: read inp directly (uncoalesced but correct)
__global__ __launch_bounds__(64) void scan_fused(const float* __restrict__ inp,
                                                 const float* __restrict__ alpha_logits,
                                                 const float* __restrict__ gamma_logits,
                                                 const float* __restrict__ k_vals,
                                                 float* __restrict__ out) {
    int b = blockIdx.x * 64 + threadIdx.x;
    const Params P = load_params(alpha_logits, gamma_logits, k_vals);
    float sL = 0.0f, sR = 0.0f, lam = 0.5f;
    float* op = out + (size_t)b * (2 * TS);
    for (int w = 0; w < NW; ++w) {
        const float4* p = reinterpret_cast<const float4*>(inp + (size_t)b * (3 * TS) + (size_t)w * 24);
        float4 q0 = p[0], q1 = p[1], q2 = p[2], q3 = p[3], q4 = p[4], q5 = p[5];
        float c[8] = {q0.x, q0.w, q1.z, q2.y, q3.x, q3.w, q4.z, q5.y};
        float o[8] = {q0.z, q1.y, q2.x, q2.w, q3.z, q4.y, q5.x, q5.w};
        unsigned word = 0;
#pragma unroll
        for (int i = 0; i < 8; ++i) {
            unsigned j = ((c[i] == 0.0f) ? 2u : 0u) | ((o[i] == 0.0f) ? 1u : 0u);
            word |= j << (2 * i);
        }
#pragma unroll
        for (int i = 0; i < 8; ++i) {
            float2 r = step_b(word, i, sL, sR, lam, P);
            reinterpret_cast<float2*>(op)[w * 8 + i] = r;
        }
    }
}

extern "C" void kernel_launch(void* const* d_in, const int* in_sizes, int n_in,
                              void* d_out, int out_size, void* d_ws, size_t ws_size,
                              hipStream_t stream) {
    const float* inp          = (const float*)d_in[0];
    const float* alpha_logits = (const float*)d_in[1];
    const float* gamma_logits = (const float*)d_in[2];
    const float* k_vals       = (const float*)d_in[3];
    float* out = (float*)d_out;

    const size_t packedB = (size_t)NG4 * BS * 4 * sizeof(unsigned int);  // 2 MiB

    if (ws_size >= packedB) {
        unsigned int* packed = (unsigned int*)d_ws;
        int total = BS * NW;
        pack_kernel<<<(total + 255) / 256, 256, 0, stream>>>(inp, packed);
        scan_spec<<<(NSPC * BS) / 256, 256, 0, stream>>>((const uint4*)packed,
                                                         alpha_logits, gamma_logits,
                                                         k_vals, out);
    } else {
        scan_fused<<<BS / 64, 64, 0, stream>>>(inp, alpha_logits, gamma_logits, k_vals, out);
    }
}